// Round 10
// baseline (84.823 us; speedup 1.0000x reference)
//
#include <hip/hip_runtime.h>
#include <hip/hip_fp16.h>
#include <math.h>

#define N_  2
#define C_  128
#define H_  128
#define W_  128
#define G_  4
#define GC_ 32
#define P_  9
#define WT  16
#define X1S 132
#define OFS 73

#define DESC_BYTES ((size_t)N_ * H_ * W_ * G_ * P_ * 16)   // 18.9 MB
#define X1BF_BYTES ((size_t)N_ * H_ * W_ * C_ * 2)         // 8.4 MB

union HU { __half h; unsigned short u; };
static __device__ __forceinline__ unsigned int f2h(float f) {
    HU x; x.h = __float2half(f); return (unsigned int)x.u;
}
static __device__ __forceinline__ float h2f(unsigned int v) {
    HU x; x.u = (unsigned short)v; return __half2float(x.h);
}
static __device__ __forceinline__ unsigned short f2bf(float f) {
    unsigned int u = __float_as_uint(f);
    u += 0x7FFFu + ((u >> 16) & 1u);
    return (unsigned short)(u >> 16);
}

// A&S 7.1.26 erf, |err| <= 1.5e-7, ~15 instructions, no branches.
static __device__ __forceinline__ float erf_fast(float x) {
    const float ax = fabsf(x);
    const float t  = __builtin_amdgcn_rcpf(fmaf(0.3275911f, ax, 1.0f));
    float p = fmaf(1.061405429f, t, -1.453152027f);
    p = fmaf(p, t, 1.421413741f);
    p = fmaf(p, t, -0.284496736f);
    p = fmaf(p, t, 0.254829592f);
    p = p * t;
    const float e = __expf(-ax * ax);
    const float y = fmaf(-p, e, 1.0f);
    return copysignf(y, x);
}

using bf16x8 = __attribute__((ext_vector_type(8))) short;
using f32x4  = __attribute__((ext_vector_type(4))) float;

// ===================== K0: depthwise conv + LN + GELU -> x1g (bf16 NHWC) =====================
// 1024 blocks x 256 thr. Block = 32 px of one row. Direct global float4 window loads.
// thread = (pq = t&7 -> 4 px, cg = t>>3 -> 4 ch). LDS: red 2x[4][32] + stat[64] = 1.3 KB.
__global__ __launch_bounds__(256, 6)
void dcn_conv(const float* __restrict__ inp,   // [N,C,H,W]
              const float* __restrict__ dww,   // [3,3,1,C]
              const float* __restrict__ dwb,   // [C]
              const float* __restrict__ lng,   // [C]
              const float* __restrict__ lnb,   // [C]
              unsigned short* __restrict__ x1g)// [N*H*W, C] bf16
{
    __shared__ float red1[4][32];
    __shared__ float red2[4][32];
    __shared__ float stat[64];

    const int t   = threadIdx.x;
    const int bid = blockIdx.x;
    const int sw  = ((bid & 7) << 7) | (bid >> 3);   // 1024 = 8 XCD x 128
    const int wq  = sw & 3;
    const int h   = (sw >> 2) & (H_ - 1);
    const int n   = sw >> 9;
    const int w0  = wq * 32;
    const int pixbase = (n * H_ + h) * W_ + w0;

    const int pq = t & 7;
    const int cg = t >> 3;
    const int c0 = cg * 4;
    const int bcol = w0 + 4 * pq - 4;

    float acc[4][4];                 // [ch][j]
    {
        const float4 bias = *(const float4*)&dwb[c0];
        #pragma unroll
        for (int ch = 0; ch < 4; ++ch)
            #pragma unroll
            for (int j = 0; j < 4; ++j) acc[ch][j] = ((const float*)&bias)[ch];
    }
    const float4 z4 = make_float4(0.f, 0.f, 0.f, 0.f);
    #pragma unroll
    for (int r = 0; r < 3; ++r) {
        const int hr = h - 1 + r;
        const bool rv = (hr >= 0) && (hr < H_);
        const float4 wr0 = *(const float4*)&dww[(r * 3 + 0) * C_ + c0];
        const float4 wr1 = *(const float4*)&dww[(r * 3 + 1) * C_ + c0];
        const float4 wr2 = *(const float4*)&dww[(r * 3 + 2) * C_ + c0];
        #pragma unroll
        for (int ch = 0; ch < 4; ++ch) {
            const float* row = inp + (((size_t)n * C_ + (c0 + ch)) * H_ + hr) * W_;
            const float4 A = (rv && bcol >= 0)   ? *(const float4*)&row[bcol]     : z4;
            const float4 B = rv                  ? *(const float4*)&row[bcol + 4] : z4;
            const float4 Cc= (rv && bcol <= 116) ? *(const float4*)&row[bcol + 8] : z4;
            const float v0 = A.w, v1 = B.x, v2 = B.y, v3 = B.z, v4 = B.w, v5 = Cc.x;
            const float k0 = ((const float*)&wr0)[ch];
            const float k1 = ((const float*)&wr1)[ch];
            const float k2 = ((const float*)&wr2)[ch];
            acc[ch][0] = fmaf(v0, k0, acc[ch][0]);
            acc[ch][0] = fmaf(v1, k1, acc[ch][0]);
            acc[ch][0] = fmaf(v2, k2, acc[ch][0]);
            acc[ch][1] = fmaf(v1, k0, acc[ch][1]);
            acc[ch][1] = fmaf(v2, k1, acc[ch][1]);
            acc[ch][1] = fmaf(v3, k2, acc[ch][1]);
            acc[ch][2] = fmaf(v2, k0, acc[ch][2]);
            acc[ch][2] = fmaf(v3, k1, acc[ch][2]);
            acc[ch][2] = fmaf(v4, k2, acc[ch][2]);
            acc[ch][3] = fmaf(v3, k0, acc[ch][3]);
            acc[ch][3] = fmaf(v4, k1, acc[ch][3]);
            acc[ch][3] = fmaf(v5, k2, acc[ch][3]);
        }
    }

    // ---- LN partials: per px over own 4 ch, shuffle-reduce over cg within wave ----
    {
        float s1[4], s2[4];
        #pragma unroll
        for (int j = 0; j < 4; ++j) {
            s1[j] = acc[0][j] + acc[1][j] + acc[2][j] + acc[3][j];
            float q = acc[0][j] * acc[0][j];
            q = fmaf(acc[1][j], acc[1][j], q);
            q = fmaf(acc[2][j], acc[2][j], q);
            q = fmaf(acc[3][j], acc[3][j], q);
            s2[j] = q;
        }
        #pragma unroll
        for (int m = 8; m <= 32; m <<= 1) {
            #pragma unroll
            for (int j = 0; j < 4; ++j) {
                s1[j] += __shfl_xor(s1[j], m);
                s2[j] += __shfl_xor(s2[j], m);
            }
        }
        const int lane = t & 63;
        const int wave = t >> 6;
        if ((lane >> 3) == 0) {
            #pragma unroll
            for (int j = 0; j < 4; ++j) {
                red1[wave][4 * pq + j] = s1[j];
                red2[wave][4 * pq + j] = s2[j];
            }
        }
    }
    __syncthreads();
    if (t < 32) {
        float s1 = 0.f, s2 = 0.f;
        #pragma unroll
        for (int w = 0; w < 4; ++w) { s1 += red1[w][t]; s2 += red2[w][t]; }
        const float mean = s1 * (1.f / 128.f);
        const float var  = s2 * (1.f / 128.f) - mean * mean;
        stat[t]      = mean;
        stat[32 + t] = rsqrtf(var + 1e-6f);
    }
    __syncthreads();

    // ---- LN + GELU (fast erf) + bf16 store ----
    {
        const float4 lg = *(const float4*)&lng[c0];
        const float4 lb = *(const float4*)&lnb[c0];
        #pragma unroll
        for (int j = 0; j < 4; ++j) {
            const int px = 4 * pq + j;
            const float mean = stat[px];
            const float rstd = stat[32 + px];
            ushort4 o;
            unsigned short* op = (unsigned short*)&o;
            #pragma unroll
            for (int ch = 0; ch < 4; ++ch) {
                float v = (acc[ch][j] - mean) * rstd * ((const float*)&lg)[ch]
                          + ((const float*)&lb)[ch];
                v = 0.5f * v * (1.f + erf_fast(v * 0.70710678118654752440f));
                op[ch] = f2bf(v);
            }
            *(ushort4*)&x1g[(size_t)(pixbase + px) * C_ + c0] = o;
        }
    }
}

// ===================== K1: MFMA offset GEMM + descriptor pack =====================
// 512 blocks x 256 thr (4 waves). Block = 64 px.
#define K1_X1T_SLOT 19456
#define K1_ARENA    (19456 + 21760)

__global__ __launch_bounds__(256, 2)
void dcn_offs(const unsigned short* __restrict__ x1g,  // [N*H*W, C] bf16
              const float* __restrict__ offw,          // [72,C]
              const float* __restrict__ offb,          // [72]
              uint4* __restrict__ desc)                // [N*H*W, 36]
{
    __shared__ __align__(16) char arena[K1_ARENA];
    unsigned short* x1t   = (unsigned short*)arena;                  // [64][136]
    float*          offs  = (float*)arena;                           // [64][76] (alias)
    unsigned short* offwt = (unsigned short*)(arena + K1_X1T_SLOT);  // [80][136]

    const int t   = threadIdx.x;
    const int bid = blockIdx.x;
    const int sw  = ((bid & 7) << 6) | (bid >> 3);     // 512 = 8 XCD x 64
    const int wh  = sw & 1;
    const int h   = (sw >> 1) & (H_ - 1);
    const int n   = sw >> 8;
    const int w0  = wh * 64;
    const int pixbase = (n * H_ + h) * W_ + w0;

    {
        const uint4* src = (const uint4*)(x1g + (size_t)pixbase * C_);
        #pragma unroll
        for (int k = 0; k < 4; ++k) {
            const int i  = t + 256 * k;      // 1024 uint4
            const int p2 = i >> 4;
            const int u  = i & 15;
            *(uint4*)&x1t[p2 * 136 + u * 8] = src[i];
        }
    }
    {
        const float4* src = (const float4*)offw;
        #pragma unroll
        for (int k = 0; k < 9; ++k) {
            const int i = t + 256 * k;       // 2304 float4
            const int o = i >> 5;
            const int u = i & 31;
            const float4 v = src[i];
            *(ushort4*)&offwt[o * 136 + u * 4] =
                make_ushort4(f2bf(v.x), f2bf(v.y), f2bf(v.z), f2bf(v.w));
        }
    }
    __syncthreads();

    const int lane = t & 63;
    const int wave = t >> 6;
    const int m16  = lane & 15;
    const int kb   = lane >> 4;
    bf16x8 afr[4];
    {
        const int apx = wave * 16 + m16;
        #pragma unroll
        for (int st = 0; st < 4; ++st)
            afr[st] = *(const bf16x8*)&x1t[apx * 136 + st * 32 + kb * 8];
    }
    float bias[5];
    #pragma unroll
    for (int nt = 0; nt < 5; ++nt) {
        const int o = nt * 16 + m16;
        bias[nt] = (o < 72) ? offb[o] : 0.f;
    }
    __syncthreads();   // x1t dead -> offs may be written

    #pragma unroll
    for (int nt = 0; nt < 5; ++nt) {
        const int orow = nt * 16 + m16;
        bf16x8 b0 = *(const bf16x8*)&offwt[orow * 136 + 0 * 32 + kb * 8];
        bf16x8 b1 = *(const bf16x8*)&offwt[orow * 136 + 1 * 32 + kb * 8];
        bf16x8 b2 = *(const bf16x8*)&offwt[orow * 136 + 2 * 32 + kb * 8];
        bf16x8 b3 = *(const bf16x8*)&offwt[orow * 136 + 3 * 32 + kb * 8];
        f32x4 acc = {bias[nt], bias[nt], bias[nt], bias[nt]};
        acc = __builtin_amdgcn_mfma_f32_16x16x32_bf16(afr[0], b0, acc, 0, 0, 0);
        acc = __builtin_amdgcn_mfma_f32_16x16x32_bf16(afr[1], b1, acc, 0, 0, 0);
        acc = __builtin_amdgcn_mfma_f32_16x16x32_bf16(afr[2], b2, acc, 0, 0, 0);
        acc = __builtin_amdgcn_mfma_f32_16x16x32_bf16(afr[3], b3, acc, 0, 0, 0);
        if (orow < 72) {
            #pragma unroll
            for (int reg = 0; reg < 4; ++reg) {
                const int pxl = wave * 16 + kb * 4 + reg;
                offs[pxl * 76 + orow] = acc[reg];
            }
        }
    }
    __syncthreads();

    #pragma unroll 1
    for (int k = 0; k < 9; ++k) {
        const int tap = t + 256 * k;         // 0..2303
        const int pix = tap / 36;
        const int rem = tap - pix * 36;
        const int g   = rem / 9;
        const int p   = rem - g * 9;
        const float ox = offs[pix * 76 + g * 18 + 2 * p];
        const float oy = offs[pix * 76 + g * 18 + 2 * p + 1];
        const float fy = (float)(h + (p % 3)) + oy;
        const float fx = (float)(w0 + pix + (p / 3)) + ox;
        const float y0f = floorf(fy);
        const float x0f = floorf(fx);
        const float wy = fy - y0f;
        const float wx = fx - x0f;
        const int y0 = (int)y0f;
        const int x0 = (int)x0f;
        const int yc0 = min(max(y0, 1), H_) - 1;
        const int yc1 = min(max(y0 + 1, 1), H_) - 1;
        const int xc0 = min(max(x0, 1), W_) - 1;
        const int xc1 = min(max(x0 + 1, 1), W_) - 1;
        const float a0 = (1.f - wy) * ((y0 >= 1 && y0 <= H_) ? 1.f : 0.f);
        const float a1 = wy * ((y0 + 1 >= 1 && y0 + 1 <= H_) ? 1.f : 0.f);
        const float b0 = (1.f - wx) * ((x0 >= 1 && x0 <= W_) ? 1.f : 0.f);
        const float b1 = wx * ((x0 + 1 >= 1 && x0 + 1 <= W_) ? 1.f : 0.f);
        const unsigned int i00 = (unsigned int)(yc0 * W_ + xc0);
        const unsigned int i01 = (unsigned int)(yc0 * W_ + xc1);
        const unsigned int i10 = (unsigned int)(yc1 * W_ + xc0);
        const unsigned int i11 = (unsigned int)(yc1 * W_ + xc1);
        desc[(size_t)pixbase * 36 + tap] =
            make_uint4(i00 | (i01 << 16),
                       i10 | (i11 << 16),
                       f2h(a0 * b0) | (f2h(a0 * b1) << 16),
                       f2h(a1 * b0) | (f2h(a1 * b1) << 16));
    }
}

// ===================== K2: pure gather (fp32, known-good) =====================
__global__ __launch_bounds__(512, 4)
void dcn_gather(const float* __restrict__ xin,   // [N,H,W,C]
                const uint4* __restrict__ desc,  // [N*H*W, 36]
                float* __restrict__ out)         // [N,C,H,W]
{
    __shared__ __align__(16) float stage[WT * X1S];

    const int t   = threadIdx.x;
    const int bid = blockIdx.x;
    const int sw  = ((bid & 7) << 8) | (bid >> 3);
    const int wt  = sw & 7;
    const int h   = (sw >> 3) & (H_ - 1);
    const int n   = sw >> 10;
    const int w0  = wt * WT;
    const int pixbase = (n * H_ + h) * W_ + w0;

    {
        const int k   = t & 7;
        const int pl  = t >> 3;
        const int pix = pl >> 2;
        const int g   = pl & 3;
        const uint4* dp = desc + (size_t)(pixbase + pix) * 36 + g * 9;
        const float4* xg = (const float4*)xin + (size_t)n * (H_ * W_ * (C_ / 4)) + g * (GC_ / 4) + k;

        uint4 d[9];
        #pragma unroll
        for (int p = 0; p < P_; ++p) d[p] = dp[p];

        float4 acc = make_float4(0.f, 0.f, 0.f, 0.f);
        #pragma unroll
        for (int p = 0; p < P_; ++p) {
            const float4 v00 = xg[(d[p].x & 0xFFFFu) * 32u];
            const float4 v01 = xg[(d[p].x >> 16) * 32u];
            const float4 v10 = xg[(d[p].y & 0xFFFFu) * 32u];
            const float4 v11 = xg[(d[p].y >> 16) * 32u];
            const float w00 = h2f(d[p].z & 0xFFFFu), w01 = h2f(d[p].z >> 16);
            const float w10 = h2f(d[p].w & 0xFFFFu), w11 = h2f(d[p].w >> 16);
            acc.x = fmaf(w00, v00.x, acc.x);
            acc.y = fmaf(w00, v00.y, acc.y);
            acc.z = fmaf(w00, v00.z, acc.z);
            acc.w = fmaf(w00, v00.w, acc.w);
            acc.x = fmaf(w01, v01.x, acc.x);
            acc.y = fmaf(w01, v01.y, acc.y);
            acc.z = fmaf(w01, v01.z, acc.z);
            acc.w = fmaf(w01, v01.w, acc.w);
            acc.x = fmaf(w10, v10.x, acc.x);
            acc.y = fmaf(w10, v10.y, acc.y);
            acc.z = fmaf(w10, v10.z, acc.z);
            acc.w = fmaf(w10, v10.w, acc.w);
            acc.x = fmaf(w11, v11.x, acc.x);
            acc.y = fmaf(w11, v11.y, acc.y);
            acc.z = fmaf(w11, v11.z, acc.z);
            acc.w = fmaf(w11, v11.w, acc.w);
        }
        *(float4*)&stage[pix * X1S + g * GC_ + k * 4] = acc;
    }
    __syncthreads();
    {
        const int pix = t & 15;
        const int c0  = t >> 4;
        #pragma unroll
        for (int i = 0; i < 4; ++i) {
            const int c = c0 + 32 * i;
            out[(((size_t)n * C_ + c) * H_ + h) * W_ + w0 + pix] = stage[pix * X1S + c];
        }
    }
}

// ===================== fallback: monolithic (fp32) =====================
#define ARENA_BYTES 22336
__global__ __launch_bounds__(256, 6)
void dcn_fused_mono(const float* __restrict__ inp, const float* __restrict__ xin,
                    const float* __restrict__ dww, const float* __restrict__ dwb,
                    const float* __restrict__ lng, const float* __restrict__ lnb,
                    const float* __restrict__ offw, const float* __restrict__ offb,
                    float* __restrict__ out)
{
    __shared__ __align__(16) char arena[ARENA_BYTES];
    float*  x1     = (float*)arena;
    uint4*  desc4  = (uint4*)(arena + 8448);
    float*  red1   = (float*)(arena + 8448);
    float*  red2   = (float*)(arena + 9472);
    float*  offs   = (float*)(arena + 17664);

    const int t   = threadIdx.x;
    const int bid = blockIdx.x;
    const int sw  = ((bid & 7) << 8) | (bid >> 3);
    const int wt  = sw & 7;
    const int h   = (sw >> 3) & (H_ - 1);
    const int n   = sw >> 10;
    const int w0  = wt * WT;

    {
        const int w = t & 15;
        const int q = t >> 4;
        float s1 = 0.f, s2 = 0.f;
        const int wcb = w0 + w - 1;
        #pragma unroll
        for (int i = 0; i < 8; ++i) {
            const int c = q * 8 + i;
            float acc = dwb[c];
            #pragma unroll
            for (int r = 0; r < 3; ++r) {
                const int hr = h - 1 + r;
                const bool rv = (hr >= 0) && (hr < H_);
                const float* row = inp + (((size_t)n * C_ + c) * H_ + hr) * W_;
                #pragma unroll
                for (int s = 0; s < 3; ++s) {
                    const int wc = wcb + s;
                    const float v = (rv && wc >= 0 && wc < W_) ? row[wc] : 0.f;
                    acc = fmaf(v, dww[(r * 3 + s) * C_ + c], acc);
                }
            }
            x1[w * X1S + c] = acc;
            s1 += acc;
            s2 = fmaf(acc, acc, s2);
        }
        red1[q * 16 + w] = s1;
        red2[q * 16 + w] = s2;
    }
    __syncthreads();
    {
        const int w = t & 15;
        const int q = t >> 4;
        float s1 = 0.f, s2 = 0.f;
        #pragma unroll
        for (int j = 0; j < 16; ++j) { s1 += red1[j * 16 + w]; s2 += red2[j * 16 + w]; }
        const float mean = s1 * (1.f / 128.f);
        const float var  = s2 * (1.f / 128.f) - mean * mean;
        const float rstd = rsqrtf(var + 1e-6f);
        #pragma unroll
        for (int i = 0; i < 8; ++i) {
            const int c = q * 8 + i;
            float v = x1[w * X1S + c];
            v = (v - mean) * rstd * lng[c] + lnb[c];
            v = 0.5f * v * (1.f + erff(v * 0.70710678118654752440f));
            x1[w * X1S + c] = v;
        }
    }
    __syncthreads();
    {
        const int pix  = t & 15;
        const int s    = t >> 4;
        const bool has5 = (s < 8);
        float acc[5];
        #pragma unroll
        for (int j = 0; j < 4; ++j) acc[j] = offb[s * 4 + j];
        acc[4] = has5 ? offb[64 + s] : 0.f;
        #pragma unroll 1
        for (int cb = 0; cb < C_; cb += 8) {
            const float4 xa = *(const float4*)&x1[pix * X1S + cb];
            const float4 xb = *(const float4*)&x1[pix * X1S + cb + 4];
            #pragma unroll
            for (int j = 0; j < 4; ++j) {
                const int o = s * 4 + j;
                const float4 wa = *(const float4*)&offw[o * C_ + cb];
                const float4 wb = *(const float4*)&offw[o * C_ + cb + 4];
                acc[j] = fmaf(xa.x, wa.x, acc[j]);
                acc[j] = fmaf(xa.y, wa.y, acc[j]);
                acc[j] = fmaf(xa.z, wa.z, acc[j]);
                acc[j] = fmaf(xa.w, wa.w, acc[j]);
                acc[j] = fmaf(xb.x, wb.x, acc[j]);
                acc[j] = fmaf(xb.y, wb.y, acc[j]);
                acc[j] = fmaf(xb.z, wb.z, acc[j]);
                acc[j] = fmaf(xb.w, wb.w, acc[j]);
            }
            if (has5) {
                const int o = 64 + s;
                const float4 wa = *(const float4*)&offw[o * C_ + cb];
                const float4 wb = *(const float4*)&offw[o * C_ + cb + 4];
                acc[4] = fmaf(xa.x, wa.x, acc[4]);
                acc[4] = fmaf(xa.y, wa.y, acc[4]);
                acc[4] = fmaf(xa.z, wa.z, acc[4]);
                acc[4] = fmaf(xa.w, wa.w, acc[4]);
                acc[4] = fmaf(xb.x, wb.x, acc[4]);
                acc[4] = fmaf(xb.y, wb.y, acc[4]);
                acc[4] = fmaf(xb.z, wb.z, acc[4]);
                acc[4] = fmaf(xb.w, wb.w, acc[4]);
            }
        }
        #pragma unroll
        for (int j = 0; j < 4; ++j) offs[pix * OFS + s * 4 + j] = acc[j];
        if (has5) offs[pix * OFS + 64 + s] = acc[4];
    }
    __syncthreads();
    {
        for (int tap = t; tap < WT * G_ * P_; tap += 256) {
            const int pg  = tap / 9;
            const int p   = tap - pg * 9;
            const int pix = pg >> 2;
            const int g   = pg & 3;
            const float ox = offs[pix * OFS + g * 18 + 2 * p];
            const float oy = offs[pix * OFS + g * 18 + 2 * p + 1];
            const float fy = (float)(h + (p % 3)) + oy;
            const float fx = (float)(w0 + pix + (p / 3)) + ox;
            const float y0f = floorf(fy);
            const float x0f = floorf(fx);
            const float wy = fy - y0f;
            const float wx = fx - x0f;
            const int y0 = (int)y0f;
            const int x0 = (int)x0f;
            const int yc0 = min(max(y0, 1), H_) - 1;
            const int yc1 = min(max(y0 + 1, 1), H_) - 1;
            const int xc0 = min(max(x0, 1), W_) - 1;
            const int xc1 = min(max(x0 + 1, 1), W_) - 1;
            const float a0 = (1.f - wy) * ((y0 >= 1 && y0 <= H_) ? 1.f : 0.f);
            const float a1 = wy * ((y0 + 1 >= 1 && y0 + 1 <= H_) ? 1.f : 0.f);
            const float b0 = (1.f - wx) * ((x0 >= 1 && x0 <= W_) ? 1.f : 0.f);
            const float b1 = wx * ((x0 + 1 >= 1 && x0 + 1 <= W_) ? 1.f : 0.f);
            const unsigned int i00 = (unsigned int)(yc0 * W_ + xc0);
            const unsigned int i01 = (unsigned int)(yc0 * W_ + xc1);
            const unsigned int i10 = (unsigned int)(yc1 * W_ + xc0);
            const unsigned int i11 = (unsigned int)(yc1 * W_ + xc1);
            desc4[tap] = make_uint4(i00 | (i01 << 16),
                                    i10 | (i11 << 16),
                                    f2h(a0 * b0) | (f2h(a0 * b1) << 16),
                                    f2h(a1 * b0) | (f2h(a1 * b1) << 16));
        }
    }
    __syncthreads();
    {
        const int k    = t & 15;
        const int slot = t >> 4;
        const float2* xb2 = (const float2*)xin + (size_t)n * (H_ * W_ * C_ / 2) + k;
        float2* st = (float2*)x1;
        #pragma unroll 1
        for (int it = 0; it < 2; ++it) {
            const int pairA = it * 32 + slot;
            const int pairB = pairA + 16;
            const int pixA = pairA >> 2, gA = pairA & 3;
            const int pixB = pairB >> 2, gB = pairB & 3;
            const float2* xgA = xb2 + gA * (GC_ / 2);
            const float2* xgB = xb2 + gB * (GC_ / 2);
            const uint4* dAp = desc4 + pairA * 9;
            const uint4* dBp = desc4 + pairB * 9;
            float aAx = 0.f, aAy = 0.f, aBx = 0.f, aBy = 0.f;
            #pragma unroll
            for (int p = 0; p < P_; ++p) {
                const uint4 da = dAp[p];
                const uint4 db = dBp[p];
                const float2 vA00 = xgA[(da.x & 0xFFFFu) * 64u];
                const float2 vA01 = xgA[(da.x >> 16) * 64u];
                const float2 vA10 = xgA[(da.y & 0xFFFFu) * 64u];
                const float2 vA11 = xgA[(da.y >> 16) * 64u];
                const float2 vB00 = xgB[(db.x & 0xFFFFu) * 64u];
                const float2 vB01 = xgB[(db.x >> 16) * 64u];
                const float2 vB10 = xgB[(db.y & 0xFFFFu) * 64u];
                const float2 vB11 = xgB[(db.y >> 16) * 64u];
                const float wA00 = h2f(da.z & 0xFFFFu), wA01 = h2f(da.z >> 16);
                const float wA10 = h2f(da.w & 0xFFFFu), wA11 = h2f(da.w >> 16);
                const float wB00 = h2f(db.z & 0xFFFFu), wB01 = h2f(db.z >> 16);
                const float wB10 = h2f(db.w & 0xFFFFu), wB11 = h2f(db.w >> 16);
                aAx = fmaf(wA00, vA00.x, aAx); aAy = fmaf(wA00, vA00.y, aAy);
                aAx = fmaf(wA01, vA01.x, aAx); aAy = fmaf(wA01, vA01.y, aAy);
                aAx = fmaf(wA10, vA10.x, aAx); aAy = fmaf(wA10, vA10.y, aAy);
                aAx = fmaf(wA11, vA11.x, aAx); aAy = fmaf(wA11, vA11.y, aAy);
                aBx = fmaf(wB00, vB00.x, aBx); aBy = fmaf(wB00, vB00.y, aBy);
                aBx = fmaf(wB01, vB01.x, aBx); aBy = fmaf(wB01, vB01.y, aBy);
                aBx = fmaf(wB10, vB10.x, aBx); aBy = fmaf(wB10, vB10.y, aBy);
                aBx = fmaf(wB11, vB11.x, aBx); aBy = fmaf(wB11, vB11.y, aBy);
            }
            st[pixA * (X1S / 2) + gA * (GC_ / 2) + k] = make_float2(aAx, aAy);
            st[pixB * (X1S / 2) + gB * (GC_ / 2) + k] = make_float2(aBx, aBy);
        }
    }
    __syncthreads();
    {
        const int pix = t & 15;
        const int cq  = t >> 4;
        #pragma unroll
        for (int i = 0; i < 8; ++i) {
            const int c = cq * 8 + i;
            out[(((size_t)n * C_ + c) * H_ + h) * W_ + w0 + pix] = x1[pix * X1S + c];
        }
    }
}

extern "C" void kernel_launch(void* const* d_in, const int* in_sizes, int n_in,
                              void* d_out, int out_size, void* d_ws, size_t ws_size,
                              hipStream_t stream) {
    const float* inp  = (const float*)d_in[0];
    const float* xin  = (const float*)d_in[1];
    const float* dww  = (const float*)d_in[2];
    const float* dwb  = (const float*)d_in[3];
    const float* lng  = (const float*)d_in[4];
    const float* lnb  = (const float*)d_in[5];
    const float* offw = (const float*)d_in[6];
    const float* offb = (const float*)d_in[7];
    float* outp = (float*)d_out;

    if (ws_size >= DESC_BYTES + X1BF_BYTES) {
        uint4* desc = (uint4*)d_ws;
        unsigned short* x1g = (unsigned short*)((char*)d_ws + DESC_BYTES);
        dcn_conv<<<dim3(1024), dim3(256), 0, stream>>>(
            inp, dww, dwb, lng, lnb, x1g);
        dcn_offs<<<dim3(512), dim3(256), 0, stream>>>(
            x1g, offw, offb, desc);
        dcn_gather<<<dim3(2048), dim3(512), 0, stream>>>(
            xin, desc, outp);
    } else {
        dcn_fused_mono<<<dim3(N_ * H_ * (W_ / WT)), dim3(256), 0, stream>>>(
            inp, xin, dww, dwb, lng, lnb, offw, offb, outp);
    }
}

// Round 11
// 53.622 us; speedup vs baseline: 1.5819x; 1.5819x over previous
//
#include <hip/hip_runtime.h>
#include <hip/hip_fp16.h>
#include <math.h>

#define N_  2
#define C_  128
#define H_  128
#define W_  128
#define G_  4
#define GC_ 32
#define P_  9
#define WT  16
#define X1S 132
#define OFS 73

#define DESC_BYTES ((size_t)N_ * H_ * W_ * G_ * P_ * 16)   // 18.9 MB

union HU { __half h; unsigned short u; };
static __device__ __forceinline__ unsigned int f2h(float f) {
    HU x; x.h = __float2half(f); return (unsigned int)x.u;
}
static __device__ __forceinline__ float h2f(unsigned int v) {
    HU x; x.u = (unsigned short)v; return __half2float(x.h);
}
static __device__ __forceinline__ unsigned short f2bf(float f) {
    unsigned int u = __float_as_uint(f);
    u += 0x7FFFu + ((u >> 16) & 1u);
    return (unsigned short)(u >> 16);
}
static __device__ __forceinline__ float bflo(unsigned int u) {
    return __uint_as_float(u << 16);
}
static __device__ __forceinline__ float bfhi(unsigned int u) {
    return __uint_as_float(u & 0xFFFF0000u);
}
static __device__ __forceinline__ float bf2f(unsigned short u) {
    return __uint_as_float(((unsigned int)u) << 16);
}

// A&S 7.1.26 erf, |err| <= 1.5e-7 (verified R10: absmax unchanged)
static __device__ __forceinline__ float erf_fast(float x) {
    const float ax = fabsf(x);
    const float t  = __builtin_amdgcn_rcpf(fmaf(0.3275911f, ax, 1.0f));
    float p = fmaf(1.061405429f, t, -1.453152027f);
    p = fmaf(p, t, 1.421413741f);
    p = fmaf(p, t, -0.284496736f);
    p = fmaf(p, t, 0.254829592f);
    p = p * t;
    const float e = __expf(-ax * ax);
    const float y = fmaf(-p, e, 1.0f);
    return copysignf(y, x);
}

using bf16x8 = __attribute__((ext_vector_type(8))) short;
using f32x4  = __attribute__((ext_vector_type(4))) float;

// ===================== K1: fused conv + LN + GELU + MFMA offset GEMM + desc =====================
// 2048 blocks x 256 thr (4 waves). Block = 16 px of one row. x1 never leaves LDS.
// LDS arena (38528 B -> 4 blocks/CU):
//   [0,     18432)  inb bf16[384 segs][24 cols]   (conv staging)
//       x1t  bf16[16][136] aliases [0, 4352)      (post-conv)
//       stat f32[32]       aliases [4480, 4608)
//       offs f32[16][76]   aliases [8192, 13056)  (MFMA out)
//   [18432, 18688)  red1 f32[4][16]
//   [18688, 18944)  red2 f32[4][16]
//   [18944, 38528)  offwt bf16[72][136]
#define K1_X1T   0
#define K1_STAT  4480
#define K1_OFFS  8192
#define K1_RED1  18432
#define K1_RED2  18688
#define K1_OFFW  18944
#define K1_ARENA 38528

__global__ __launch_bounds__(256, 4)
void dcn_convoffs(const float* __restrict__ inp,   // [N,C,H,W]
                  const float* __restrict__ dww,   // [3,3,1,C]
                  const float* __restrict__ dwb,   // [C]
                  const float* __restrict__ lng,   // [C]
                  const float* __restrict__ lnb,   // [C]
                  const float* __restrict__ offw,  // [72,C]
                  const float* __restrict__ offb,  // [72]
                  uint4* __restrict__ desc)        // [N*H*W, 36]
{
    __shared__ __align__(16) char arena[K1_ARENA];
    unsigned short* inb   = (unsigned short*)arena;               // [384][24]
    unsigned short* x1t   = (unsigned short*)(arena + K1_X1T);    // [16][136] alias
    float*          stat  = (float*)(arena + K1_STAT);            // [32] alias
    float*          offs  = (float*)(arena + K1_OFFS);            // [16][76] alias
    float* red1 = (float*)(arena + K1_RED1);                      // [4][16]
    float* red2 = (float*)(arena + K1_RED2);
    unsigned short* offwt = (unsigned short*)(arena + K1_OFFW);   // [72][136]

    const int t   = threadIdx.x;
    const int bid = blockIdx.x;
    const int sw  = ((bid & 7) << 8) | (bid >> 3);   // 2048 = 8 XCD x 256
    const int wq  = sw & 7;
    const int h   = (sw >> 3) & (H_ - 1);
    const int n   = sw >> 10;
    const int w0  = wq * 16;
    const int pixbase = (n * H_ + h) * W_ + w0;

    // ---- stage input window (bf16, cols w0-4..w0+19) + offw (bf16) ----
    {
        #pragma unroll
        for (int k = 0; k < 9; ++k) {
            const int q   = t + 256 * k;     // 0..2303
            const int seg = q / 6;
            const int i   = q - seg * 6;
            const int c   = seg / 3;
            const int r   = seg - c * 3;
            const int hr  = h - 1 + r;
            const int col0 = w0 - 4 + 4 * i;
            float4 v = make_float4(0.f, 0.f, 0.f, 0.f);
            if (hr >= 0 && hr < H_ && col0 >= 0 && col0 <= W_ - 4)
                v = *(const float4*)&inp[(((size_t)n * C_ + c) * H_ + hr) * W_ + col0];
            *(ushort4*)&inb[seg * 24 + 4 * i] =
                make_ushort4(f2bf(v.x), f2bf(v.y), f2bf(v.z), f2bf(v.w));
        }
        const float4* src = (const float4*)offw;
        #pragma unroll
        for (int k = 0; k < 9; ++k) {
            const int i = t + 256 * k;       // 2304 float4
            const int o = i >> 5;
            const int u = i & 31;
            const float4 v = src[i];
            *(ushort4*)&offwt[o * 136 + u * 4] =
                make_ushort4(f2bf(v.x), f2bf(v.y), f2bf(v.z), f2bf(v.w));
        }
    }
    __syncthreads();

    // ---- conv: thread = (pq = t&3 -> 4 px, cg = t>>2 -> 2 ch) ----
    const int pq = t & 3;
    const int cg = t >> 2;
    const int c0 = cg * 2;
    float acc[2][4];                 // [ch][j]
    {
        const float2 bias = *(const float2*)&dwb[c0];
        #pragma unroll
        for (int j = 0; j < 4; ++j) { acc[0][j] = bias.x; acc[1][j] = bias.y; }
        #pragma unroll
        for (int r = 0; r < 3; ++r) {
            const float2 wd0 = *(const float2*)&dww[(r * 3 + 0) * C_ + c0];
            const float2 wd1 = *(const float2*)&dww[(r * 3 + 1) * C_ + c0];
            const float2 wd2 = *(const float2*)&dww[(r * 3 + 2) * C_ + c0];
            #pragma unroll
            for (int ch = 0; ch < 2; ++ch) {
                const int seg = (c0 + ch) * 3 + r;
                const unsigned short* rp = &inb[seg * 24 + 4 * pq];
                const uint2 a = *(const uint2*)rp;        // s0..s3
                const uint2 b = *(const uint2*)(rp + 4);  // s4..s7
                const unsigned int s8 = rp[8];
                const float v3 = bfhi(a.y);
                const float v4 = bflo(b.x);
                const float v5 = bfhi(b.x);
                const float v6 = bflo(b.y);
                const float v7 = bfhi(b.y);
                const float v8 = bflo(s8);
                const float k0 = ch ? wd0.y : wd0.x;
                const float k1 = ch ? wd1.y : wd1.x;
                const float k2 = ch ? wd2.y : wd2.x;
                acc[ch][0] = fmaf(v3, k0, acc[ch][0]);
                acc[ch][0] = fmaf(v4, k1, acc[ch][0]);
                acc[ch][0] = fmaf(v5, k2, acc[ch][0]);
                acc[ch][1] = fmaf(v4, k0, acc[ch][1]);
                acc[ch][1] = fmaf(v5, k1, acc[ch][1]);
                acc[ch][1] = fmaf(v6, k2, acc[ch][1]);
                acc[ch][2] = fmaf(v5, k0, acc[ch][2]);
                acc[ch][2] = fmaf(v6, k1, acc[ch][2]);
                acc[ch][2] = fmaf(v7, k2, acc[ch][2]);
                acc[ch][3] = fmaf(v6, k0, acc[ch][3]);
                acc[ch][3] = fmaf(v7, k1, acc[ch][3]);
                acc[ch][3] = fmaf(v8, k2, acc[ch][3]);
            }
        }
    }

    // ---- LN partials: shuffle-reduce over the 16 cg within each wave ----
    {
        float s1[4], s2[4];
        #pragma unroll
        for (int j = 0; j < 4; ++j) {
            s1[j] = acc[0][j] + acc[1][j];
            s2[j] = fmaf(acc[1][j], acc[1][j], acc[0][j] * acc[0][j]);
        }
        #pragma unroll
        for (int m = 4; m <= 32; m <<= 1) {
            #pragma unroll
            for (int j = 0; j < 4; ++j) {
                s1[j] += __shfl_xor(s1[j], m);
                s2[j] += __shfl_xor(s2[j], m);
            }
        }
        const int lane = t & 63;
        const int wave = t >> 6;
        if ((lane >> 2) == 0) {              // lanes 0..3 (one per pq)
            #pragma unroll
            for (int j = 0; j < 4; ++j) {
                red1[wave * 16 + 4 * pq + j] = s1[j];
                red2[wave * 16 + 4 * pq + j] = s2[j];
            }
        }
    }
    __syncthreads();
    if (t < 16) {
        float s1 = 0.f, s2 = 0.f;
        #pragma unroll
        for (int w = 0; w < 4; ++w) { s1 += red1[w * 16 + t]; s2 += red2[w * 16 + t]; }
        const float mean = s1 * (1.f / 128.f);
        const float var  = s2 * (1.f / 128.f) - mean * mean;
        stat[t]      = mean;
        stat[16 + t] = rsqrtf(var + 1e-6f);
    }
    __syncthreads();

    // ---- LN + GELU (fast erf) -> x1t bf16 (aliases dead inb region) ----
    {
        const float2 lg = *(const float2*)&lng[c0];
        const float2 lb = *(const float2*)&lnb[c0];
        #pragma unroll
        for (int j = 0; j < 4; ++j) {
            const int px = 4 * pq + j;
            const float mean = stat[px];
            const float rstd = stat[16 + px];
            float v0 = (acc[0][j] - mean) * rstd * lg.x + lb.x;
            float v1 = (acc[1][j] - mean) * rstd * lg.y + lb.y;
            v0 = 0.5f * v0 * (1.f + erf_fast(v0 * 0.70710678118654752440f));
            v1 = 0.5f * v1 * (1.f + erf_fast(v1 * 0.70710678118654752440f));
            *(ushort2*)&x1t[px * 136 + c0] = make_ushort2(f2bf(v0), f2bf(v1));
        }
    }
    __syncthreads();

    // ---- MFMA offset GEMM: 16px x 72o x K128 (wave w -> n-tile w; wave 0 also nt 4) ----
    {
        const int lane = t & 63;
        const int wave = t >> 6;
        const int m16  = lane & 15;
        const int kb   = lane >> 4;
        bf16x8 afr[4];
        #pragma unroll
        for (int st = 0; st < 4; ++st)
            afr[st] = *(const bf16x8*)&x1t[m16 * 136 + st * 32 + kb * 8];
        #pragma unroll
        for (int pass = 0; pass < 2; ++pass) {
            const int nt = (pass == 0) ? wave : 4;
            if (pass == 1 && wave != 0) break;   // wave-uniform
            const int orow = nt * 16 + m16;
            const bool ov = (orow < 72);
            const int orc = ov ? orow : 0;
            const bf16x8 b0 = *(const bf16x8*)&offwt[orc * 136 + 0 * 32 + kb * 8];
            const bf16x8 b1 = *(const bf16x8*)&offwt[orc * 136 + 1 * 32 + kb * 8];
            const bf16x8 b2 = *(const bf16x8*)&offwt[orc * 136 + 2 * 32 + kb * 8];
            const bf16x8 b3 = *(const bf16x8*)&offwt[orc * 136 + 3 * 32 + kb * 8];
            const float bias = ov ? offb[orow] : 0.f;
            f32x4 a4 = {bias, bias, bias, bias};
            a4 = __builtin_amdgcn_mfma_f32_16x16x32_bf16(afr[0], b0, a4, 0, 0, 0);
            a4 = __builtin_amdgcn_mfma_f32_16x16x32_bf16(afr[1], b1, a4, 0, 0, 0);
            a4 = __builtin_amdgcn_mfma_f32_16x16x32_bf16(afr[2], b2, a4, 0, 0, 0);
            a4 = __builtin_amdgcn_mfma_f32_16x16x32_bf16(afr[3], b3, a4, 0, 0, 0);
            if (ov) {
                #pragma unroll
                for (int reg = 0; reg < 4; ++reg) {
                    const int pxl = kb * 4 + reg;
                    offs[pxl * 76 + orow] = a4[reg];
                }
            }
        }
    }
    __syncthreads();

    // ---- descriptor pack: 16 px x 36 taps = 576 ----
    for (int tap = t; tap < 16 * 36; tap += 256) {
        const int pix = tap / 36;
        const int rem = tap - pix * 36;
        const int g   = rem / 9;
        const int p   = rem - g * 9;
        const float ox = offs[pix * 76 + g * 18 + 2 * p];
        const float oy = offs[pix * 76 + g * 18 + 2 * p + 1];
        const float fy = (float)(h + (p % 3)) + oy;
        const float fx = (float)(w0 + pix + (p / 3)) + ox;
        const float y0f = floorf(fy);
        const float x0f = floorf(fx);
        const float wy = fy - y0f;
        const float wx = fx - x0f;
        const int y0 = (int)y0f;
        const int x0 = (int)x0f;
        const int yc0 = min(max(y0, 1), H_) - 1;
        const int yc1 = min(max(y0 + 1, 1), H_) - 1;
        const int xc0 = min(max(x0, 1), W_) - 1;
        const int xc1 = min(max(x0 + 1, 1), W_) - 1;
        const float a0 = (1.f - wy) * ((y0 >= 1 && y0 <= H_) ? 1.f : 0.f);
        const float a1 = wy * ((y0 + 1 >= 1 && y0 + 1 <= H_) ? 1.f : 0.f);
        const float b0 = (1.f - wx) * ((x0 >= 1 && x0 <= W_) ? 1.f : 0.f);
        const float b1 = wx * ((x0 + 1 >= 1 && x0 + 1 <= W_) ? 1.f : 0.f);
        const unsigned int i00 = (unsigned int)(yc0 * W_ + xc0);
        const unsigned int i01 = (unsigned int)(yc0 * W_ + xc1);
        const unsigned int i10 = (unsigned int)(yc1 * W_ + xc0);
        const unsigned int i11 = (unsigned int)(yc1 * W_ + xc1);
        desc[(size_t)pixbase * 36 + tap] =
            make_uint4(i00 | (i01 << 16),
                       i10 | (i11 << 16),
                       f2h(a0 * b0) | (f2h(a0 * b1) << 16),
                       f2h(a1 * b0) | (f2h(a1 * b1) << 16));
    }
}

// ===================== K2: pure gather (fp32, known-good) =====================
__global__ __launch_bounds__(512, 4)
void dcn_gather(const float* __restrict__ xin,   // [N,H,W,C]
                const uint4* __restrict__ desc,  // [N*H*W, 36]
                float* __restrict__ out)         // [N,C,H,W]
{
    __shared__ __align__(16) float stage[WT * X1S];

    const int t   = threadIdx.x;
    const int bid = blockIdx.x;
    const int sw  = ((bid & 7) << 8) | (bid >> 3);
    const int wt  = sw & 7;
    const int h   = (sw >> 3) & (H_ - 1);
    const int n   = sw >> 10;
    const int w0  = wt * WT;
    const int pixbase = (n * H_ + h) * W_ + w0;

    {
        const int k   = t & 7;
        const int pl  = t >> 3;
        const int pix = pl >> 2;
        const int g   = pl & 3;
        const uint4* dp = desc + (size_t)(pixbase + pix) * 36 + g * 9;
        const float4* xg = (const float4*)xin + (size_t)n * (H_ * W_ * (C_ / 4)) + g * (GC_ / 4) + k;

        uint4 d[9];
        #pragma unroll
        for (int p = 0; p < P_; ++p) d[p] = dp[p];

        float4 acc = make_float4(0.f, 0.f, 0.f, 0.f);
        #pragma unroll
        for (int p = 0; p < P_; ++p) {
            const float4 v00 = xg[(d[p].x & 0xFFFFu) * 32u];
            const float4 v01 = xg[(d[p].x >> 16) * 32u];
            const float4 v10 = xg[(d[p].y & 0xFFFFu) * 32u];
            const float4 v11 = xg[(d[p].y >> 16) * 32u];
            const float w00 = h2f(d[p].z & 0xFFFFu), w01 = h2f(d[p].z >> 16);
            const float w10 = h2f(d[p].w & 0xFFFFu), w11 = h2f(d[p].w >> 16);
            acc.x = fmaf(w00, v00.x, acc.x);
            acc.y = fmaf(w00, v00.y, acc.y);
            acc.z = fmaf(w00, v00.z, acc.z);
            acc.w = fmaf(w00, v00.w, acc.w);
            acc.x = fmaf(w01, v01.x, acc.x);
            acc.y = fmaf(w01, v01.y, acc.y);
            acc.z = fmaf(w01, v01.z, acc.z);
            acc.w = fmaf(w01, v01.w, acc.w);
            acc.x = fmaf(w10, v10.x, acc.x);
            acc.y = fmaf(w10, v10.y, acc.y);
            acc.z = fmaf(w10, v10.z, acc.z);
            acc.w = fmaf(w10, v10.w, acc.w);
            acc.x = fmaf(w11, v11.x, acc.x);
            acc.y = fmaf(w11, v11.y, acc.y);
            acc.z = fmaf(w11, v11.z, acc.z);
            acc.w = fmaf(w11, v11.w, acc.w);
        }
        *(float4*)&stage[pix * X1S + g * GC_ + k * 4] = acc;
    }
    __syncthreads();
    {
        const int pix = t & 15;
        const int c0  = t >> 4;
        #pragma unroll
        for (int i = 0; i < 4; ++i) {
            const int c = c0 + 32 * i;
            out[(((size_t)n * C_ + c) * H_ + h) * W_ + w0 + pix] = stage[pix * X1S + c];
        }
    }
}

// ===================== fallback: monolithic (fp32) =====================
#define ARENA_BYTES 22336
__global__ __launch_bounds__(256, 6)
void dcn_fused_mono(const float* __restrict__ inp, const float* __restrict__ xin,
                    const float* __restrict__ dww, const float* __restrict__ dwb,
                    const float* __restrict__ lng, const float* __restrict__ lnb,
                    const float* __restrict__ offw, const float* __restrict__ offb,
                    float* __restrict__ out)
{
    __shared__ __align__(16) char arena[ARENA_BYTES];
    float*  x1     = (float*)arena;
    uint4*  desc4  = (uint4*)(arena + 8448);
    float*  red1   = (float*)(arena + 8448);
    float*  red2   = (float*)(arena + 9472);
    float*  offs   = (float*)(arena + 17664);

    const int t   = threadIdx.x;
    const int bid = blockIdx.x;
    const int sw  = ((bid & 7) << 8) | (bid >> 3);
    const int wt  = sw & 7;
    const int h   = (sw >> 3) & (H_ - 1);
    const int n   = sw >> 10;
    const int w0  = wt * WT;

    {
        const int w = t & 15;
        const int q = t >> 4;
        float s1 = 0.f, s2 = 0.f;
        const int wcb = w0 + w - 1;
        #pragma unroll
        for (int i = 0; i < 8; ++i) {
            const int c = q * 8 + i;
            float acc = dwb[c];
            #pragma unroll
            for (int r = 0; r < 3; ++r) {
                const int hr = h - 1 + r;
                const bool rv = (hr >= 0) && (hr < H_);
                const float* row = inp + (((size_t)n * C_ + c) * H_ + hr) * W_;
                #pragma unroll
                for (int s = 0; s < 3; ++s) {
                    const int wc = wcb + s;
                    const float v = (rv && wc >= 0 && wc < W_) ? row[wc] : 0.f;
                    acc = fmaf(v, dww[(r * 3 + s) * C_ + c], acc);
                }
            }
            x1[w * X1S + c] = acc;
            s1 += acc;
            s2 = fmaf(acc, acc, s2);
        }
        red1[q * 16 + w] = s1;
        red2[q * 16 + w] = s2;
    }
    __syncthreads();
    {
        const int w = t & 15;
        const int q = t >> 4;
        float s1 = 0.f, s2 = 0.f;
        #pragma unroll
        for (int j = 0; j < 16; ++j) { s1 += red1[j * 16 + w]; s2 += red2[j * 16 + w]; }
        const float mean = s1 * (1.f / 128.f);
        const float var  = s2 * (1.f / 128.f) - mean * mean;
        const float rstd = rsqrtf(var + 1e-6f);
        #pragma unroll
        for (int i = 0; i < 8; ++i) {
            const int c = q * 8 + i;
            float v = x1[w * X1S + c];
            v = (v - mean) * rstd * lng[c] + lnb[c];
            v = 0.5f * v * (1.f + erff(v * 0.70710678118654752440f));
            x1[w * X1S + c] = v;
        }
    }
    __syncthreads();
    {
        const int pix  = t & 15;
        const int s    = t >> 4;
        const bool has5 = (s < 8);
        float acc[5];
        #pragma unroll
        for (int j = 0; j < 4; ++j) acc[j] = offb[s * 4 + j];
        acc[4] = has5 ? offb[64 + s] : 0.f;
        #pragma unroll 1
        for (int cb = 0; cb < C_; cb += 8) {
            const float4 xa = *(const float4*)&x1[pix * X1S + cb];
            const float4 xb = *(const float4*)&x1[pix * X1S + cb + 4];
            #pragma unroll
            for (int j = 0; j < 4; ++j) {
                const int o = s * 4 + j;
                const float4 wa = *(const float4*)&offw[o * C_ + cb];
                const float4 wb = *(const float4*)&offw[o * C_ + cb + 4];
                acc[j] = fmaf(xa.x, wa.x, acc[j]);
                acc[j] = fmaf(xa.y, wa.y, acc[j]);
                acc[j] = fmaf(xa.z, wa.z, acc[j]);
                acc[j] = fmaf(xa.w, wa.w, acc[j]);
                acc[j] = fmaf(xb.x, wb.x, acc[j]);
                acc[j] = fmaf(xb.y, wb.y, acc[j]);
                acc[j] = fmaf(xb.z, wb.z, acc[j]);
                acc[j] = fmaf(xb.w, wb.w, acc[j]);
            }
            if (has5) {
                const int o = 64 + s;
                const float4 wa = *(const float4*)&offw[o * C_ + cb];
                const float4 wb = *(const float4*)&offw[o * C_ + cb + 4];
                acc[4] = fmaf(xa.x, wa.x, acc[4]);
                acc[4] = fmaf(xa.y, wa.y, acc[4]);
                acc[4] = fmaf(xa.z, wa.z, acc[4]);
                acc[4] = fmaf(xa.w, wa.w, acc[4]);
                acc[4] = fmaf(xb.x, wb.x, acc[4]);
                acc[4] = fmaf(xb.y, wb.y, acc[4]);
                acc[4] = fmaf(xb.z, wb.z, acc[4]);
                acc[4] = fmaf(xb.w, wb.w, acc[4]);
            }
        }
        #pragma unroll
        for (int j = 0; j < 4; ++j) offs[pix * OFS + s * 4 + j] = acc[j];
        if (has5) offs[pix * OFS + 64 + s] = acc[4];
    }
    __syncthreads();
    {
        for (int tap = t; tap < WT * G_ * P_; tap += 256) {
            const int pg  = tap / 9;
            const int p   = tap - pg * 9;
            const int pix = pg >> 2;
            const int g   = pg & 3;
            const float ox = offs[pix * OFS + g * 18 + 2 * p];
            const float oy = offs[pix * OFS + g * 18 + 2 * p + 1];
            const float fy = (float)(h + (p % 3)) + oy;
            const float fx = (float)(w0 + pix + (p / 3)) + ox;
            const float y0f = floorf(fy);
            const float x0f = floorf(fx);
            const float wy = fy - y0f;
            const float wx = fx - x0f;
            const int y0 = (int)y0f;
            const int x0 = (int)x0f;
            const int yc0 = min(max(y0, 1), H_) - 1;
            const int yc1 = min(max(y0 + 1, 1), H_) - 1;
            const int xc0 = min(max(x0, 1), W_) - 1;
            const int xc1 = min(max(x0 + 1, 1), W_) - 1;
            const float a0 = (1.f - wy) * ((y0 >= 1 && y0 <= H_) ? 1.f : 0.f);
            const float a1 = wy * ((y0 + 1 >= 1 && y0 + 1 <= H_) ? 1.f : 0.f);
            const float b0 = (1.f - wx) * ((x0 >= 1 && x0 <= W_) ? 1.f : 0.f);
            const float b1 = wx * ((x0 + 1 >= 1 && x0 + 1 <= W_) ? 1.f : 0.f);
            const unsigned int i00 = (unsigned int)(yc0 * W_ + xc0);
            const unsigned int i01 = (unsigned int)(yc0 * W_ + xc1);
            const unsigned int i10 = (unsigned int)(yc1 * W_ + xc0);
            const unsigned int i11 = (unsigned int)(yc1 * W_ + xc1);
            desc4[tap] = make_uint4(i00 | (i01 << 16),
                                    i10 | (i11 << 16),
                                    f2h(a0 * b0) | (f2h(a0 * b1) << 16),
                                    f2h(a1 * b0) | (f2h(a1 * b1) << 16));
        }
    }
    __syncthreads();
    {
        const int k    = t & 15;
        const int slot = t >> 4;
        const float2* xb2 = (const float2*)xin + (size_t)n * (H_ * W_ * C_ / 2) + k;
        float2* st = (float2*)x1;
        #pragma unroll 1
        for (int it = 0; it < 2; ++it) {
            const int pairA = it * 32 + slot;
            const int pairB = pairA + 16;
            const int pixA = pairA >> 2, gA = pairA & 3;
            const int pixB = pairB >> 2, gB = pairB & 3;
            const float2* xgA = xb2 + gA * (GC_ / 2);
            const float2* xgB = xb2 + gB * (GC_ / 2);
            const uint4* dAp = desc4 + pairA * 9;
            const uint4* dBp = desc4 + pairB * 9;
            float aAx = 0.f, aAy = 0.f, aBx = 0.f, aBy = 0.f;
            #pragma unroll
            for (int p = 0; p < P_; ++p) {
                const uint4 da = dAp[p];
                const uint4 db = dBp[p];
                const float2 vA00 = xgA[(da.x & 0xFFFFu) * 64u];
                const float2 vA01 = xgA[(da.x >> 16) * 64u];
                const float2 vA10 = xgA[(da.y & 0xFFFFu) * 64u];
                const float2 vA11 = xgA[(da.y >> 16) * 64u];
                const float2 vB00 = xgB[(db.x & 0xFFFFu) * 64u];
                const float2 vB01 = xgB[(db.x >> 16) * 64u];
                const float2 vB10 = xgB[(db.y & 0xFFFFu) * 64u];
                const float2 vB11 = xgB[(db.y >> 16) * 64u];
                const float wA00 = h2f(da.z & 0xFFFFu), wA01 = h2f(da.z >> 16);
                const float wA10 = h2f(da.w & 0xFFFFu), wA11 = h2f(da.w >> 16);
                const float wB00 = h2f(db.z & 0xFFFFu), wB01 = h2f(db.z >> 16);
                const float wB10 = h2f(db.w & 0xFFFFu), wB11 = h2f(db.w >> 16);
                aAx = fmaf(wA00, vA00.x, aAx); aAy = fmaf(wA00, vA00.y, aAy);
                aAx = fmaf(wA01, vA01.x, aAx); aAy = fmaf(wA01, vA01.y, aAy);
                aAx = fmaf(wA10, vA10.x, aAx); aAy = fmaf(wA10, vA10.y, aAy);
                aAx = fmaf(wA11, vA11.x, aAx); aAy = fmaf(wA11, vA11.y, aAy);
                aBx = fmaf(wB00, vB00.x, aBx); aBy = fmaf(wB00, vB00.y, aBy);
                aBx = fmaf(wB01, vB01.x, aBx); aBy = fmaf(wB01, vB01.y, aBy);
                aBx = fmaf(wB10, vB10.x, aBx); aBy = fmaf(wB10, vB10.y, aBy);
                aBx = fmaf(wB11, vB11.x, aBx); aBy = fmaf(wB11, vB11.y, aBy);
            }
            st[pixA * (X1S / 2) + gA * (GC_ / 2) + k] = make_float2(aAx, aAy);
            st[pixB * (X1S / 2) + gB * (GC_ / 2) + k] = make_float2(aBx, aBy);
        }
    }
    __syncthreads();
    {
        const int pix = t & 15;
        const int cq  = t >> 4;
        #pragma unroll
        for (int i = 0; i < 8; ++i) {
            const int c = cq * 8 + i;
            out[(((size_t)n * C_ + c) * H_ + h) * W_ + w0 + pix] = x1[pix * X1S + c];
        }
    }
}

extern "C" void kernel_launch(void* const* d_in, const int* in_sizes, int n_in,
                              void* d_out, int out_size, void* d_ws, size_t ws_size,
                              hipStream_t stream) {
    const float* inp  = (const float*)d_in[0];
    const float* xin  = (const float*)d_in[1];
    const float* dww  = (const float*)d_in[2];
    const float* dwb  = (const float*)d_in[3];
    const float* lng  = (const float*)d_in[4];
    const float* lnb  = (const float*)d_in[5];
    const float* offw = (const float*)d_in[6];
    const float* offb = (const float*)d_in[7];
    float* outp = (float*)d_out;

    if (ws_size >= DESC_BYTES) {
        uint4* desc = (uint4*)d_ws;
        dcn_convoffs<<<dim3(2048), dim3(256), 0, stream>>>(
            inp, dww, dwb, lng, lnb, offw, offb, desc);
        dcn_gather<<<dim3(2048), dim3(512), 0, stream>>>(xin, desc, outp);
    } else {
        dcn_fused_mono<<<dim3(N_ * H_ * (W_ / WT)), dim3(256), 0, stream>>>(
            inp, xin, dww, dwb, lng, lnb, offw, offb, outp);
    }
}

// Round 12
// 41.084 us; speedup vs baseline: 2.0646x; 1.3052x over previous
//
#include <hip/hip_runtime.h>
#include <hip/hip_fp16.h>
#include <math.h>

#define N_  2
#define C_  128
#define H_  128
#define W_  128
#define G_  4
#define GC_ 32
#define P_  9
#define X1S 132

union HU { __half h; unsigned short u; };
static __device__ __forceinline__ unsigned int f2h(float f) {
    HU x; x.h = __float2half(f); return (unsigned int)x.u;
}
static __device__ __forceinline__ float h2f(unsigned int v) {
    HU x; x.u = (unsigned short)v; return __half2float(x.h);
}
static __device__ __forceinline__ unsigned short f2bf(float f) {
    unsigned int u = __float_as_uint(f);
    u += 0x7FFFu + ((u >> 16) & 1u);
    return (unsigned short)(u >> 16);
}
static __device__ __forceinline__ float bflo(unsigned int u) {
    return __uint_as_float(u << 16);
}
static __device__ __forceinline__ float bfhi(unsigned int u) {
    return __uint_as_float(u & 0xFFFF0000u);
}

// A&S 7.1.26 erf, |err| <= 1.5e-7 (verified R10/R11: absmax unchanged)
static __device__ __forceinline__ float erf_fast(float x) {
    const float ax = fabsf(x);
    const float t  = __builtin_amdgcn_rcpf(fmaf(0.3275911f, ax, 1.0f));
    float p = fmaf(1.061405429f, t, -1.453152027f);
    p = fmaf(p, t, 1.421413741f);
    p = fmaf(p, t, -0.284496736f);
    p = fmaf(p, t, 0.254829592f);
    p = p * t;
    const float e = __expf(-ax * ax);
    const float y = fmaf(-p, e, 1.0f);
    return copysignf(y, x);
}

using bf16x8 = __attribute__((ext_vector_type(8))) short;
using f32x4  = __attribute__((ext_vector_type(4))) float;

// ============ fully fused: conv + LN + GELU + MFMA offs + desc(LDS) + gather + out ============
// 2048 blocks x 256 thr (4 waves). Block = 16 px of one row. NOTHING intermediate touches HBM.
// LDS arena (38528 B -> 4 blocks/CU):
//   [0,     18432)  inb bf16[384 segs][24 cols]       (conv staging; dead after conv)
//       x1t   bf16[16][136]  alias [0, 4352)          (post-conv; dead after MFMA A-loads)
//       stat  f32[32]        alias [4480, 4608)
//       offs  f32[16][76]    alias [13056, 17920)     (MFMA out; dead after desc pack)
//       stage f32[16][132]   alias [0, 8448)          (gather out; after x1t dead)
//   [18432, 18688)  red1 f32[4][16]
//   [18688, 18944)  red2 f32[4][16]
//   [18944, 38528)  offwt bf16[72][136]               (dead after MFMA)
//       desc_lds uint4[576]  alias [18944, 28160)
#define K_X1T   0
#define K_STAT  4480
#define K_OFFS  13056
#define K_RED1  18432
#define K_RED2  18688
#define K_OFFW  18944
#define K_ARENA 38528

__global__ __launch_bounds__(256, 4)
void dcn_fused(const float* __restrict__ inp,   // [N,C,H,W]
               const float* __restrict__ xin,   // [N,H,W,C]
               const float* __restrict__ dww,   // [3,3,1,C]
               const float* __restrict__ dwb,   // [C]
               const float* __restrict__ lng,   // [C]
               const float* __restrict__ lnb,   // [C]
               const float* __restrict__ offw,  // [72,C]
               const float* __restrict__ offb,  // [72]
               float* __restrict__ out)         // [N,C,H,W]
{
    __shared__ __align__(16) char arena[K_ARENA];
    unsigned short* inb   = (unsigned short*)arena;               // [384][24]
    unsigned short* x1t   = (unsigned short*)(arena + K_X1T);     // [16][136] alias
    float*          stat  = (float*)(arena + K_STAT);             // [32] alias
    float*          offs  = (float*)(arena + K_OFFS);             // [16][76] alias
    float*          stage = (float*)arena;                        // [16][132] alias
    float* red1 = (float*)(arena + K_RED1);                       // [4][16]
    float* red2 = (float*)(arena + K_RED2);
    unsigned short* offwt = (unsigned short*)(arena + K_OFFW);    // [72][136]
    uint4* desc_lds = (uint4*)(arena + K_OFFW);                   // [576] alias

    const int t   = threadIdx.x;
    const int bid = blockIdx.x;
    const int sw  = ((bid & 7) << 8) | (bid >> 3);   // 2048 = 8 XCD x 256
    const int wq  = sw & 7;
    const int h   = (sw >> 3) & (H_ - 1);
    const int n   = sw >> 10;
    const int w0  = wq * 16;

    // ---- P1: stage input window (bf16, cols w0-4..w0+19) + offw (bf16) ----
    {
        #pragma unroll
        for (int k = 0; k < 9; ++k) {
            const int q   = t + 256 * k;     // 0..2303
            const int seg = q / 6;
            const int i   = q - seg * 6;
            const int c   = seg / 3;
            const int r   = seg - c * 3;
            const int hr  = h - 1 + r;
            const int col0 = w0 - 4 + 4 * i;
            float4 v = make_float4(0.f, 0.f, 0.f, 0.f);
            if (hr >= 0 && hr < H_ && col0 >= 0 && col0 <= W_ - 4)
                v = *(const float4*)&inp[(((size_t)n * C_ + c) * H_ + hr) * W_ + col0];
            *(ushort4*)&inb[seg * 24 + 4 * i] =
                make_ushort4(f2bf(v.x), f2bf(v.y), f2bf(v.z), f2bf(v.w));
        }
        const float4* src = (const float4*)offw;
        #pragma unroll
        for (int k = 0; k < 9; ++k) {
            const int i = t + 256 * k;       // 2304 float4
            const int o = i >> 5;
            const int u = i & 31;
            const float4 v = src[i];
            *(ushort4*)&offwt[o * 136 + u * 4] =
                make_ushort4(f2bf(v.x), f2bf(v.y), f2bf(v.z), f2bf(v.w));
        }
    }
    __syncthreads();

    // ---- P2: conv (pq = t&3 -> 4 px, cg = t>>2 -> 2 ch) ----
    const int pq = t & 3;
    const int cg = t >> 2;
    const int c0 = cg * 2;
    float acc[2][4];
    {
        const float2 bias = *(const float2*)&dwb[c0];
        #pragma unroll
        for (int j = 0; j < 4; ++j) { acc[0][j] = bias.x; acc[1][j] = bias.y; }
        #pragma unroll
        for (int r = 0; r < 3; ++r) {
            const float2 wd0 = *(const float2*)&dww[(r * 3 + 0) * C_ + c0];
            const float2 wd1 = *(const float2*)&dww[(r * 3 + 1) * C_ + c0];
            const float2 wd2 = *(const float2*)&dww[(r * 3 + 2) * C_ + c0];
            #pragma unroll
            for (int ch = 0; ch < 2; ++ch) {
                const int seg = (c0 + ch) * 3 + r;
                const unsigned short* rp = &inb[seg * 24 + 4 * pq];
                const uint2 a = *(const uint2*)rp;
                const uint2 b = *(const uint2*)(rp + 4);
                const unsigned int s8 = rp[8];
                const float v3 = bfhi(a.y);
                const float v4 = bflo(b.x);
                const float v5 = bfhi(b.x);
                const float v6 = bflo(b.y);
                const float v7 = bfhi(b.y);
                const float v8 = bflo(s8);
                const float k0 = ch ? wd0.y : wd0.x;
                const float k1 = ch ? wd1.y : wd1.x;
                const float k2 = ch ? wd2.y : wd2.x;
                acc[ch][0] = fmaf(v3, k0, acc[ch][0]);
                acc[ch][0] = fmaf(v4, k1, acc[ch][0]);
                acc[ch][0] = fmaf(v5, k2, acc[ch][0]);
                acc[ch][1] = fmaf(v4, k0, acc[ch][1]);
                acc[ch][1] = fmaf(v5, k1, acc[ch][1]);
                acc[ch][1] = fmaf(v6, k2, acc[ch][1]);
                acc[ch][2] = fmaf(v5, k0, acc[ch][2]);
                acc[ch][2] = fmaf(v6, k1, acc[ch][2]);
                acc[ch][2] = fmaf(v7, k2, acc[ch][2]);
                acc[ch][3] = fmaf(v6, k0, acc[ch][3]);
                acc[ch][3] = fmaf(v7, k1, acc[ch][3]);
                acc[ch][3] = fmaf(v8, k2, acc[ch][3]);
            }
        }
    }

    // ---- P3: LN partials (shuffle over 16 cg/wave, then 4 waves via red) ----
    {
        float s1[4], s2[4];
        #pragma unroll
        for (int j = 0; j < 4; ++j) {
            s1[j] = acc[0][j] + acc[1][j];
            s2[j] = fmaf(acc[1][j], acc[1][j], acc[0][j] * acc[0][j]);
        }
        #pragma unroll
        for (int m = 4; m <= 32; m <<= 1) {
            #pragma unroll
            for (int j = 0; j < 4; ++j) {
                s1[j] += __shfl_xor(s1[j], m);
                s2[j] += __shfl_xor(s2[j], m);
            }
        }
        const int lane = t & 63;
        const int wave = t >> 6;
        if ((lane >> 2) == 0) {
            #pragma unroll
            for (int j = 0; j < 4; ++j) {
                red1[wave * 16 + 4 * pq + j] = s1[j];
                red2[wave * 16 + 4 * pq + j] = s2[j];
            }
        }
    }
    __syncthreads();
    if (t < 16) {
        float s1 = 0.f, s2 = 0.f;
        #pragma unroll
        for (int w = 0; w < 4; ++w) { s1 += red1[w * 16 + t]; s2 += red2[w * 16 + t]; }
        const float mean = s1 * (1.f / 128.f);
        const float var  = s2 * (1.f / 128.f) - mean * mean;
        stat[t]      = mean;
        stat[16 + t] = rsqrtf(var + 1e-6f);
    }
    __syncthreads();

    // ---- P4: LN + GELU -> x1t bf16 ----
    {
        const float2 lg = *(const float2*)&lng[c0];
        const float2 lb = *(const float2*)&lnb[c0];
        #pragma unroll
        for (int j = 0; j < 4; ++j) {
            const int px = 4 * pq + j;
            const float mean = stat[px];
            const float rstd = stat[16 + px];
            float v0 = (acc[0][j] - mean) * rstd * lg.x + lb.x;
            float v1 = (acc[1][j] - mean) * rstd * lg.y + lb.y;
            v0 = 0.5f * v0 * (1.f + erf_fast(v0 * 0.70710678118654752440f));
            v1 = 0.5f * v1 * (1.f + erf_fast(v1 * 0.70710678118654752440f));
            *(ushort2*)&x1t[px * 136 + c0] = make_ushort2(f2bf(v0), f2bf(v1));
        }
    }
    __syncthreads();

    // ---- P5: MFMA offset GEMM: 16px x 72o x K128 ----
    {
        const int lane = t & 63;
        const int wave = t >> 6;
        const int m16  = lane & 15;
        const int kb   = lane >> 4;
        bf16x8 afr[4];
        #pragma unroll
        for (int st = 0; st < 4; ++st)
            afr[st] = *(const bf16x8*)&x1t[m16 * 136 + st * 32 + kb * 8];
        #pragma unroll
        for (int pass = 0; pass < 2; ++pass) {
            const int nt = (pass == 0) ? wave : 4;
            if (pass == 1 && wave != 0) break;   // wave-uniform
            const int orow = nt * 16 + m16;
            const bool ov = (orow < 72);
            const int orc = ov ? orow : 0;
            const bf16x8 b0 = *(const bf16x8*)&offwt[orc * 136 + 0 * 32 + kb * 8];
            const bf16x8 b1 = *(const bf16x8*)&offwt[orc * 136 + 1 * 32 + kb * 8];
            const bf16x8 b2 = *(const bf16x8*)&offwt[orc * 136 + 2 * 32 + kb * 8];
            const bf16x8 b3 = *(const bf16x8*)&offwt[orc * 136 + 3 * 32 + kb * 8];
            const float bias = ov ? offb[orow] : 0.f;
            f32x4 a4 = {bias, bias, bias, bias};
            a4 = __builtin_amdgcn_mfma_f32_16x16x32_bf16(afr[0], b0, a4, 0, 0, 0);
            a4 = __builtin_amdgcn_mfma_f32_16x16x32_bf16(afr[1], b1, a4, 0, 0, 0);
            a4 = __builtin_amdgcn_mfma_f32_16x16x32_bf16(afr[2], b2, a4, 0, 0, 0);
            a4 = __builtin_amdgcn_mfma_f32_16x16x32_bf16(afr[3], b3, a4, 0, 0, 0);
            if (ov) {
                #pragma unroll
                for (int reg = 0; reg < 4; ++reg) {
                    const int pxl = kb * 4 + reg;
                    offs[pxl * 76 + orow] = a4[reg];   // offs @13056: no alias w/ x1t/offwt
                }
            }
        }
    }
    __syncthreads();

    // ---- P6: descriptor pack -> LDS (offwt region now dead) ----
    for (int tap = t; tap < 16 * 36; tap += 256) {
        const int pix = tap / 36;
        const int rem = tap - pix * 36;
        const int g   = rem / 9;
        const int p   = rem - g * 9;
        const float ox = offs[pix * 76 + g * 18 + 2 * p];
        const float oy = offs[pix * 76 + g * 18 + 2 * p + 1];
        const float fy = (float)(h + (p % 3)) + oy;
        const float fx = (float)(w0 + pix + (p / 3)) + ox;
        const float y0f = floorf(fy);
        const float x0f = floorf(fx);
        const float wy = fy - y0f;
        const float wx = fx - x0f;
        const int y0 = (int)y0f;
        const int x0 = (int)x0f;
        const int yc0 = min(max(y0, 1), H_) - 1;
        const int yc1 = min(max(y0 + 1, 1), H_) - 1;
        const int xc0 = min(max(x0, 1), W_) - 1;
        const int xc1 = min(max(x0 + 1, 1), W_) - 1;
        const float a0 = (1.f - wy) * ((y0 >= 1 && y0 <= H_) ? 1.f : 0.f);
        const float a1 = wy * ((y0 + 1 >= 1 && y0 + 1 <= H_) ? 1.f : 0.f);
        const float b0 = (1.f - wx) * ((x0 >= 1 && x0 <= W_) ? 1.f : 0.f);
        const float b1 = wx * ((x0 + 1 >= 1 && x0 + 1 <= W_) ? 1.f : 0.f);
        const unsigned int i00 = (unsigned int)(yc0 * W_ + xc0);
        const unsigned int i01 = (unsigned int)(yc0 * W_ + xc1);
        const unsigned int i10 = (unsigned int)(yc1 * W_ + xc0);
        const unsigned int i11 = (unsigned int)(yc1 * W_ + xc1);
        desc_lds[tap] = make_uint4(i00 | (i01 << 16),
                                   i10 | (i11 << 16),
                                   f2h(a0 * b0) | (f2h(a0 * b1) << 16),
                                   f2h(a1 * b0) | (f2h(a1 * b1) << 16));
    }
    __syncthreads();

    // ---- P7: gather (desc from LDS, x from global) -> stage ----
    {
        const int k  = t & 7;        // channel quad within group
        const int pl = t >> 3;       // 0..31
        const float4* xb = (const float4*)xin + (size_t)n * (H_ * W_ * (C_ / 4)) + k;
        #pragma unroll
        for (int it = 0; it < 2; ++it) {
            const int pair = it * 32 + pl;   // 0..63 = pix*4+g
            const int pix  = pair >> 2;
            const int g    = pair & 3;
            const uint4* dp = desc_lds + pair * 9;
            const float4* xg = xb + g * (GC_ / 4);
            uint4 d[9];
            #pragma unroll
            for (int p = 0; p < P_; ++p) d[p] = dp[p];
            float4 a4 = make_float4(0.f, 0.f, 0.f, 0.f);
            #pragma unroll
            for (int p = 0; p < P_; ++p) {
                const float4 v00 = xg[(d[p].x & 0xFFFFu) * 32u];
                const float4 v01 = xg[(d[p].x >> 16) * 32u];
                const float4 v10 = xg[(d[p].y & 0xFFFFu) * 32u];
                const float4 v11 = xg[(d[p].y >> 16) * 32u];
                const float w00 = h2f(d[p].z & 0xFFFFu), w01 = h2f(d[p].z >> 16);
                const float w10 = h2f(d[p].w & 0xFFFFu), w11 = h2f(d[p].w >> 16);
                a4.x = fmaf(w00, v00.x, a4.x);
                a4.y = fmaf(w00, v00.y, a4.y);
                a4.z = fmaf(w00, v00.z, a4.z);
                a4.w = fmaf(w00, v00.w, a4.w);
                a4.x = fmaf(w01, v01.x, a4.x);
                a4.y = fmaf(w01, v01.y, a4.y);
                a4.z = fmaf(w01, v01.z, a4.z);
                a4.w = fmaf(w01, v01.w, a4.w);
                a4.x = fmaf(w10, v10.x, a4.x);
                a4.y = fmaf(w10, v10.y, a4.y);
                a4.z = fmaf(w10, v10.z, a4.z);
                a4.w = fmaf(w10, v10.w, a4.w);
                a4.x = fmaf(w11, v11.x, a4.x);
                a4.y = fmaf(w11, v11.y, a4.y);
                a4.z = fmaf(w11, v11.z, a4.z);
                a4.w = fmaf(w11, v11.w, a4.w);
            }
            *(float4*)&stage[pix * X1S + g * GC_ + k * 4] = a4;  // stage @0: x1t dead
        }
    }
    __syncthreads();

    // ---- P8: NCHW write (16-px contiguous segments) ----
    {
        const int pix = t & 15;
        const int cq  = t >> 4;      // 0..15
        #pragma unroll
        for (int i = 0; i < 8; ++i) {
            const int c = cq + 16 * i;
            out[(((size_t)n * C_ + c) * H_ + h) * W_ + w0 + pix] = stage[pix * X1S + c];
        }
    }
}

extern "C" void kernel_launch(void* const* d_in, const int* in_sizes, int n_in,
                              void* d_out, int out_size, void* d_ws, size_t ws_size,
                              hipStream_t stream) {
    const float* inp  = (const float*)d_in[0];
    const float* xin  = (const float*)d_in[1];
    const float* dww  = (const float*)d_in[2];
    const float* dwb  = (const float*)d_in[3];
    const float* lng  = (const float*)d_in[4];
    const float* lnb  = (const float*)d_in[5];
    const float* offw = (const float*)d_in[6];
    const float* offb = (const float*)d_in[7];
    float* outp = (float*)d_out;

    dcn_fused<<<dim3(2048), dim3(256), 0, stream>>>(
        inp, xin, dww, dwb, lng, lnb, offw, offb, outp);
}